// Round 12
// baseline (325.745 us; speedup 1.0000x reference)
//
#include <hip/hip_runtime.h>
#include <hip/hip_fp8.h>
#include <hip/hip_fp16.h>

// Problem constants: N=50000, E=1.6M, dims 512 -> 128 -> 64
#define IN_DIM  512
#define HID_DIM 128
#define OUT_DIM 64

typedef unsigned short ushort_t;
typedef ushort_t ushort4v __attribute__((ext_vector_type(4)));
typedef ushort_t ushort8 __attribute__((ext_vector_type(8)));
typedef __bf16  bf16x8  __attribute__((ext_vector_type(8)));
typedef float   floatx4 __attribute__((ext_vector_type(4)));
typedef unsigned uint4v __attribute__((ext_vector_type(4)));   // NT-load capable
typedef unsigned uint2v __attribute__((ext_vector_type(2)));

// fp32 -> bf16 round-to-nearest-even (bit trick; inputs are finite)
__device__ __forceinline__ ushort_t f2bf(float f) {
    union { float f; unsigned u; } v; v.f = f;
    unsigned r = v.u + 0x7FFFu + ((v.u >> 16) & 1u);
    return (ushort_t)(r >> 16);
}
__device__ __forceinline__ float bf2f(ushort_t u) {
    return __uint_as_float(((unsigned)u) << 16);
}
// fp32 <-> fp8 e4m3 (OCP fn) via HIP type (HW v_cvt on gfx950)
__device__ __forceinline__ unsigned char f2fp8(float f) {
    __hip_fp8_e4m3 t(f); return (unsigned char)t.__x;
}
__device__ __forceinline__ float fp82f(unsigned char b) {
    __hip_fp8_e4m3 t; t.__x = (__hip_fp8_storage_t)b; return (float)t;
}
// direct byte-select fp8->f32 (1 VALU op on gfx950); fallback = extract+cvt
#if __has_builtin(__builtin_amdgcn_cvt_f32_fp8)
#define FP8CVT(v, j) __builtin_amdgcn_cvt_f32_fp8((v), (j))
#else
#define FP8CVT(v, j) fp82f((unsigned char)(((v) >> ((j) * 8)) & 255u))
#endif

__global__ void k_zero(int* __restrict__ p, int n) {
    int i = blockIdx.x * blockDim.x + threadIdx.x;
    if (i < n) p[i] = 0;
}

// ---------------------------------------------------------------------------
// Pipeline (main path, 8 dispatches; exact R9 structure = best measured
// 316.6us, plus non-temporal hints on spmm streaming traffic):
//   k_wcvt2  : W1 transpose (bf16) + W2 pack (MFMA-frag order) + zero bcnt/done
//   k_bhist2 : bucket histogram; LAST finishing block runs the scan in-kernel
//   k_bin    : LDS-staged binning into bucket regions (ept)
//   k_unbin  : per-bucket scatter to final padded 4B records + rseg
//   k_gemm   : x @ W1  (BR=128 LDS double-buffered MFMA — best measured;
//              packed-W variants BR=32/BR=64 both regressed, R8/R10)
//   k_spmm1  : spmm layer1 (fp8 gather, 4-in-flight, NT ep/h)  -> h bf16
//   k_gemm_pk: h @ W2  (BR=32 packed-W, R9-proven)
//   k_spmm2  : spmm layer2 (NT ep/out) -> out
// Edge record: {col:16 | fp16 weight:16}; row segments padded to 8 records.
// ---------------------------------------------------------------------------

#define BIN_TILE 4096
#define BH_TILE  8192
#define NBMAX    512
// per-bucket slack for per-row pad-to-8 (<=128*7=896) + base 8-alignment
#define BSLACK   1032
// k_unbin LDS staging capacity; larger buckets spill to global reads
#define UNBIN_LDS 8192
// packed-W2 entries: (OUT/16 tiles) * (HID/32 steps) * 64 lanes
#define NE2 ((OUT_DIM / 16) * (HID_DIM / 32) * 64)   // 1024

// --- wcvt2: W1 transpose + W2 MFMA-frag pack + zero bcnt/done --------------
__global__ void k_wcvt2(const float* __restrict__ W1, ushort_t* __restrict__ Wt1,
                        const float* __restrict__ W2, ushort_t* __restrict__ Wpk2,
                        int* __restrict__ bcnt, int* __restrict__ done) {
    if (blockIdx.x == 0) {
        bcnt[threadIdx.x] = 0;
        bcnt[threadIdx.x + 256] = 0;
        if (threadIdx.x == 0) *done = 0;
    }
    int i = blockIdx.x * blockDim.x + threadIdx.x;
    if (i < IN_DIM * HID_DIM) {
        int k = i / HID_DIM, c = i % HID_DIM;
        Wt1[(size_t)c * IN_DIM + k] = f2bf(W1[i]);
    } else {
        int q = i - IN_DIM * HID_DIM;
        if (q < NE2) {
            int l = q & 63, rest = q >> 6;
            int s  = rest & (HID_DIM / 32 - 1);   // 0..3
            int tt = rest >> 2;                   // 0..3
            int col  = tt * 16 + (l & 15);
            int krow = s * 32 + ((l >> 4) << 3);
            ushort8 v;
#pragma unroll
            for (int j = 0; j < 8; ++j)
                v[j] = f2bf(W2[(size_t)(krow + j) * OUT_DIM + col]);
            *reinterpret_cast<ushort8*>(Wpk2 + (size_t)q * 8) = v;
        }
    }
}

// --- bhist2: LDS-privatized bucket histogram -> global atomics; the LAST
// block to finish (atomic done counter) performs the exclusive scan of
// padded counts in-kernel.  No spinning: deadlock-free by construction.
__global__ __launch_bounds__(256) void k_bhist2(const int* __restrict__ rows,
                                                int* __restrict__ bcnt,
                                                int* __restrict__ bucket_base,
                                                int* __restrict__ bucket_fill,
                                                int* __restrict__ done,
                                                int E, int nbk, int nblk) {
    __shared__ int lc[NBMAX];
    __shared__ int amLast;
    const int t = threadIdx.x;
    lc[t] = 0; lc[t + 256] = 0;
    __syncthreads();
    const int base = blockIdx.x * BH_TILE;
#pragma unroll
    for (int j = 0; j < BH_TILE / 256; ++j) {
        int e = base + t + j * 256;
        if (e < E) atomicAdd(&lc[rows[e] >> 7], 1);
    }
    __syncthreads();
    if (lc[t])       atomicAdd(&bcnt[t], lc[t]);
    if (lc[t + 256]) atomicAdd(&bcnt[t + 256], lc[t + 256]);
    __syncthreads();   // each wave drains its vmem (incl. atomics) here
    if (t == 0) {
        __threadfence();
        amLast = (atomicAdd(done, 1) == nblk - 1) ? 1 : 0;
    }
    __syncthreads();
    if (!amLast) return;

    // final block: device-scope atomic reads of the complete histogram
    int c0 = atomicAdd(&bcnt[t], 0);
    int c1 = atomicAdd(&bcnt[t + 256], 0);
    lc[t]       = (t < nbk)       ? (((c0 + 7) & ~7) + 1024) : 0;
    lc[t + 256] = (t + 256 < nbk) ? (((c1 + 7) & ~7) + 1024) : 0;
    __syncthreads();
    for (int d = 1; d < NBMAX; d <<= 1) {
        int v0 = (t >= d) ? lc[t - d] : 0;
        int v1 = (t + 256 >= d) ? lc[t + 256 - d] : 0;
        __syncthreads();
        lc[t] += v0; lc[t + 256] += v1;
        __syncthreads();
    }
#pragma unroll
    for (int l = 0; l < 2; ++l) {
        int i = t + l * 256;
        if (i < nbk) {
            int v = (i == 0) ? 0 : lc[i - 1];
            bucket_base[i] = v;
            bucket_fill[i] = v;
        }
    }
}

// Phase A: bin edges into bucket regions of ept with LDS staging.
// Record: .x = col | rowoff<<16 | bucket<<23, .y = fp16(weight) << 16.
__global__ __launch_bounds__(256) void k_bin(const int* __restrict__ rows,
                                             const int* __restrict__ cols,
                                             const float* __restrict__ ew,
                                             int* __restrict__ bucket_fill,
                                             int2* __restrict__ ept, int E, int nbk) {
    __shared__ int cnt[NBMAX], inc[NBMAX], cnt2[NBMAX], gbase[NBMAX];
    __shared__ int2 stage[BIN_TILE];
    const int t = threadIdx.x;
    const int tile0 = blockIdx.x * BIN_TILE;

    cnt[t] = 0; cnt[t + 256] = 0; cnt2[t] = 0; cnt2[t + 256] = 0;
    __syncthreads();

    int px[16], pw[16];
    int nv = 0;
#pragma unroll
    for (int j = 0; j < 16; ++j) {
        int e = tile0 + t + j * 256;
        if (e < E) {
            int r = rows[e];
            int b = r >> 7;
            px[nv] = cols[e] | ((r & 127) << 16) | (b << 23);
            pw[nv] = ((int)__half_as_ushort(__float2half(ew[e]))) << 16;
            ++nv;
            atomicAdd(&cnt[b], 1);
        }
    }
    __syncthreads();

    inc[t] = cnt[t]; inc[t + 256] = cnt[t + 256];
    __syncthreads();
    for (int d = 1; d < NBMAX; d <<= 1) {
        int v0 = (t >= d) ? inc[t - d] : 0;
        int v1 = (t + 256 >= d) ? inc[t + 256 - d] : 0;
        __syncthreads();
        inc[t] += v0; inc[t + 256] += v1;
        __syncthreads();
    }

    if (t < nbk && cnt[t] > 0)             gbase[t]       = atomicAdd(&bucket_fill[t], cnt[t]);
    if (t + 256 < nbk && cnt[t + 256] > 0) gbase[t + 256] = atomicAdd(&bucket_fill[t + 256], cnt[t + 256]);

    for (int j = 0; j < nv; ++j) {
        int b = ((unsigned)px[j]) >> 23;
        int off = (b == 0) ? 0 : inc[b - 1];
        int r = atomicAdd(&cnt2[b], 1);
        stage[off + r] = make_int2(px[j], pw[j]);
    }
    __syncthreads();

    int total = inc[nbk - 1];
    for (int s = t; s < total; s += 256) {
        int2 rec = stage[s];
        int b = ((unsigned)rec.x) >> 23;
        int off = (b == 0) ? 0 : inc[b - 1];
        ept[gbase[b] + (s - off)] = rec;
    }
}

// Phase B: one block per bucket; stages the bucket's records in LDS (single
// global read of ept), derives padded per-row segments rseg[r], scatters
// 4-byte records from LDS; pads with w=0.  Buckets > UNBIN_LDS spill.
__global__ __launch_bounds__(256) void k_unbin(const int* __restrict__ bucket_base,
                                               const int* __restrict__ bcnt,
                                               const int2* __restrict__ ept,
                                               unsigned* __restrict__ ep4,
                                               int2* __restrict__ rseg,
                                               int n) {
    __shared__ int rcnt[128], sc[128], fill[128], rbase[128];
    __shared__ int2 lrec[UNBIN_LDS];
    const int b = blockIdx.x;
    const int t = threadIdx.x;
    const int r0 = b << 7;
    const int nrows = (n - r0 < 128) ? (n - r0) : 128;
    const int bstart = bucket_base[b];
    const int cnt    = bcnt[b];
    const int inl    = (cnt < UNBIN_LDS) ? cnt : UNBIN_LDS;

    if (t < 128) rcnt[t] = 0;
    __syncthreads();

    for (int e = t; e < inl; e += 256) {
        int2 rec = ept[bstart + e];
        lrec[e] = rec;
        atomicAdd(&rcnt[(rec.x >> 16) & 127], 1);
    }
    for (int e = inl + t; e < cnt; e += 256)
        atomicAdd(&rcnt[(ept[bstart + e].x >> 16) & 127], 1);
    __syncthreads();

    if (t < 128) sc[t] = (rcnt[t] + 7) & ~7;   // padded per-row counts
    __syncthreads();
    for (int d = 1; d < 128; d <<= 1) {
        int v = (t >= d && t < 128) ? sc[t - d] : 0;
        __syncthreads();
        if (t < 128) sc[t] += v;
        __syncthreads();
    }
    if (t < 128) {
        int start = bstart + ((t == 0) ? 0 : sc[t - 1]);
        rbase[t] = start;
        fill[t]  = start;
        if (t < nrows)
            rseg[r0 + t] = make_int2(start, start + ((rcnt[t] + 7) & ~7));
    }
    __syncthreads();

    for (int e = t; e < inl; e += 256) {
        int2 rec = lrec[e];
        int ro = (rec.x >> 16) & 127;
        int p = atomicAdd(&fill[ro], 1);
        ep4[p] = ((unsigned)rec.x & 0xFFFFu) | ((unsigned)rec.y & 0xFFFF0000u);
    }
    for (int e = inl + t; e < cnt; e += 256) {
        int2 rec = ept[bstart + e];
        int ro = (rec.x >> 16) & 127;
        int p = atomicAdd(&fill[ro], 1);
        ep4[p] = ((unsigned)rec.x & 0xFFFFu) | ((unsigned)rec.y & 0xFFFF0000u);
    }
    __syncthreads();

    if (t < 128) {
        int pend = rbase[t] + ((rcnt[t] + 7) & ~7);
        for (int p = fill[t]; p < pend; ++p) ep4[p] = 0u;  // col 0, w = 0
    }
}

// --- fallback CSR build for n > 65536: hist -> 3-kernel scan -> scatter ----

__global__ void k_hist(const int* __restrict__ rows, int* __restrict__ deg, int E) {
    int i = blockIdx.x * blockDim.x + threadIdx.x;
    if (i < E) atomicAdd(&deg[rows[i]], 1);
}

#define SCAN_TILE 2048

__global__ __launch_bounds__(256) void k_scan1(const int* __restrict__ deg,
                                               int* __restrict__ bsum, int n) {
    __shared__ int s[256];
    const int tid = threadIdx.x;
    const int base = blockIdx.x * SCAN_TILE + tid * 8;
    int sum = 0;
#pragma unroll
    for (int i = 0; i < 8; ++i) { int idx = base + i; if (idx < n) sum += deg[idx]; }
    s[tid] = sum;
    __syncthreads();
#pragma unroll
    for (int off = 128; off > 0; off >>= 1) {
        if (tid < off) s[tid] += s[tid + off];
        __syncthreads();
    }
    if (tid == 0) bsum[blockIdx.x] = s[0];
}

__global__ __launch_bounds__(256) void k_scan2(const int* __restrict__ bsum,
                                               int* __restrict__ bscan, int nb) {
    __shared__ int s[256];
    const int tid = threadIdx.x;
    s[tid] = (tid < nb) ? bsum[tid] : 0;
    __syncthreads();
#pragma unroll
    for (int off = 1; off < 256; off <<= 1) {
        int v = (tid >= off) ? s[tid - off] : 0;
        __syncthreads();
        s[tid] += v;
        __syncthreads();
    }
    if (tid < nb) bscan[tid] = (tid == 0) ? 0 : s[tid - 1];
}

__global__ __launch_bounds__(256) void k_scan3(const int* __restrict__ deg,
                                               const int* __restrict__ bscan,
                                               int* __restrict__ row_ptr,
                                               int* __restrict__ row_fill,
                                               int n, int E) {
    __shared__ int s[256];
    const int tid = threadIdx.x;
    const int base = blockIdx.x * SCAN_TILE + tid * 8;
    int v[8];
#pragma unroll
    for (int i = 0; i < 8; ++i) { int idx = base + i; v[i] = (idx < n) ? deg[idx] : 0; }
    int sum = 0;
#pragma unroll
    for (int i = 0; i < 8; ++i) sum += v[i];
    s[tid] = sum;
    __syncthreads();
#pragma unroll
    for (int off = 1; off < 256; off <<= 1) {
        int t = (tid >= off) ? s[tid - off] : 0;
        __syncthreads();
        s[tid] += t;
        __syncthreads();
    }
    int run = bscan[blockIdx.x] + ((tid == 0) ? 0 : s[tid - 1]);
#pragma unroll
    for (int i = 0; i < 8; ++i) {
        int idx = base + i;
        if (idx < n) {
            row_ptr[idx]  = run;
            row_fill[idx] = run;
            run += v[i];
        }
    }
    if (blockIdx.x == 0 && tid == 0) row_ptr[n] = E;
}

__global__ void k_scatter(const int* __restrict__ rows, const int* __restrict__ cols,
                          const float* __restrict__ ew, int* __restrict__ row_fill,
                          int2* __restrict__ ep, int E) {
    int i = blockIdx.x * blockDim.x + threadIdx.x;
    if (i < E) {
        int r = rows[i];
        int p = atomicAdd(&row_fill[r], 1);
        ep[p] = make_int2(cols[i], __float_as_int(ew[i]));
    }
}

// ---------------------------------------------------------------------------
// MFMA bf16 GEMM, BR=128, LDS double-buffered, one barrier per K-step.
// (Best measured structure for the tall gemm1 across BR=32/64/128 trials.)
// ---------------------------------------------------------------------------
template <int DK, int DC, bool A_BF16, bool OUT_FP8>
__global__ __launch_bounds__(256) void k_gemm_mfma(const void* __restrict__ Av,
                                                   const ushort_t* __restrict__ Wt,
                                                   void* __restrict__ Cv, int n) {
    constexpr int BR = 128, BK = 32, NT = DC / 16, SA = 40;
    __shared__ __align__(16) ushort_t As[2][BR * SA];
    __shared__ __align__(16) ushort_t Ws[2][DC * SA];

    const int tid  = threadIdx.x;
    const int wv   = tid >> 6;
    const int lane = tid & 63;
    const int m    = lane & 15;
    const int quad = lane >> 4;
    const int row0 = blockIdx.x * BR;

    floatx4 acc[2][NT];
#pragma unroll
    for (int f = 0; f < 2; ++f)
#pragma unroll
        for (int t = 0; t < NT; ++t) acc[f][t] = (floatx4){0.f, 0.f, 0.f, 0.f};

    const int ar = tid >> 1;
    const int ak = (tid & 1) * 16;
    int arr = row0 + ar; if (arr >= n) arr = n - 1;
    const int wc = (DC == 128) ? (tid >> 1) : (tid >> 2);
    const int wk = (DC == 128) ? ((tid & 1) * 16) : ((tid & 3) * 8);

    float4 af0, af1, af2, af3;
    ushort8 ab0, ab1;
    ushort8 wr0, wr1;

#define GLOAD(K0) {                                                                          \
        if constexpr (A_BF16) {                                                              \
            const ushort_t* Ab = (const ushort_t*)Av + (size_t)arr * DK + (K0) + ak;         \
            ab0 = *reinterpret_cast<const ushort8*>(Ab);                                     \
            ab1 = *reinterpret_cast<const ushort8*>(Ab + 8);                                 \
        } else {                                                                             \
            const float* Ab = (const float*)Av + (size_t)arr * DK + (K0) + ak;               \
            af0 = *reinterpret_cast<const float4*>(Ab);                                      \
            af1 = *reinterpret_cast<const float4*>(Ab + 4);                                  \
            af2 = *reinterpret_cast<const float4*>(Ab + 8);                                  \
            af3 = *reinterpret_cast<const float4*>(Ab + 12);                                 \
        }                                                                                    \
        wr0 = *reinterpret_cast<const ushort8*>(&Wt[(size_t)wc * DK + (K0) + wk]);           \
        if constexpr (DC == 128)                                                             \
            wr1 = *reinterpret_cast<const ushort8*>(&Wt[(size_t)wc * DK + (K0) + wk + 8]);   \
    }
#define LSTORE(BUF) {                                                                        \
        ushort8 ap0, ap1;                                                                    \
        if constexpr (A_BF16) { ap0 = ab0; ap1 = ab1; }                                      \
        else {                                                                               \
            ap0 = (ushort8){ f2bf(af0.x), f2bf(af0.y), f2bf(af0.z), f2bf(af0.w),             \
                             f2bf(af1.x), f2bf(af1.y), f2bf(af1.z), f2bf(af1.w) };           \
            ap1 = (ushort8){ f2bf(af2.x), f2bf(af2.y), f2bf(af2.z), f2bf(af2.w),             \
                             f2bf(af3.x), f2bf(af3.y), f2bf(af3.z), f2bf(af3.w) };           \
        }                                                                                    \
        *reinterpret_cast<ushort8*>(&As[BUF][ar * SA + ak])     = ap0;                       \
        *reinterpret_cast<ushort8*>(&As[BUF][ar * SA + ak + 8]) = ap1;                       \
        *reinterpret_cast<ushort8*>(&Ws[BUF][wc * SA + wk]) = wr0;                           \
        if constexpr (DC == 128)                                                             \
            *reinterpret_cast<ushort8*>(&Ws[BUF][wc * SA + wk + 8]) = wr1;                   \
    }

    GLOAD(0);
    LSTORE(0);
    __syncthreads();
    int cur = 0;
#pragma unroll
    for (int k0 = 0; k0 < DK; k0 += BK) {
        const int nxt = k0 + BK;
        if (nxt < DK) GLOAD(nxt);
        bf16x8 a0 = *reinterpret_cast<bf16x8*>(&As[cur][(wv * 32 + m) * SA + quad * 8]);
        bf16x8 a1 = *reinterpret_cast<bf16x8*>(&As[cur][(wv * 32 + 16 + m) * SA + quad * 8]);
#pragma unroll
        for (int t = 0; t < NT; ++t) {
            bf16x8 bfr = *reinterpret_cast<bf16x8*>(&Ws[cur][(t * 16 + m) * SA + quad * 8]);
            acc[0][t] = __builtin_amdgcn_mfma_f32_16x16x32_bf16(a0, bfr, acc[0][t], 0, 0, 0);
            acc[1][t] = __builtin_amdgcn_mfma_f32_16x16x32_bf16(a1, bfr, acc[1][t], 0, 0, 0);
        }
        if (nxt < DK) {
            LSTORE(cur ^ 1);
            __syncthreads();
            cur ^= 1;
        }
    }
#undef GLOAD
#undef LSTORE

#pragma unroll
    for (int f = 0; f < 2; ++f) {
#pragma unroll
        for (int t = 0; t < NT; ++t) {
#pragma unroll
            for (int i = 0; i < 4; ++i) {
                int r = row0 + wv * 32 + f * 16 + quad * 4 + i;
                if (r < n) {
                    if constexpr (OUT_FP8)
                        ((unsigned char*)Cv)[(size_t)r * DC + t * 16 + m] = f2fp8(acc[f][t][i]);
                    else
                        ((ushort_t*)Cv)[(size_t)r * DC + t * 16 + m] = f2bf(acc[f][t][i]);
                }
            }
        }
    }
}

// ---------------------------------------------------------------------------
// Packed-W MFMA GEMM (R9-proven): BR=32, wave owns DC/4 cols, A-only 5KB LDS.
// Used for the small gemm2 (DC=64).
// ---------------------------------------------------------------------------
template <int DK, int DC, bool A_BF16, bool OUT_FP8>
__global__ __launch_bounds__(256) void k_gemm_pk(const void* __restrict__ Av,
                                                 const ushort_t* __restrict__ Wpk,
                                                 void* __restrict__ Cv, int n) {
    constexpr int BR = 32, BK = 32, SA = 40;
    constexpr int NTW = DC / 64;
    constexpr int NS  = DK / 32;
    __shared__ __align__(16) ushort_t As[2][BR * SA];

    const int tid  = threadIdx.x;
    const int wv   = tid >> 6;
    const int lane = tid & 63;
    const int m    = lane & 15;
    const int quad = lane >> 4;
    const int row0 = blockIdx.x * BR;
    const int cbase = wv * (DC / 4);

    floatx4 acc[2][NTW];
#pragma unroll
    for (int f = 0; f < 2; ++f)
#pragma unroll
        for (int t = 0; t < NTW; ++t) acc[f][t] = (floatx4){0.f, 0.f, 0.f, 0.f};

    const int ar = tid >> 3;
    const int ak = (tid & 7) * 4;
    int arr = row0 + ar; if (arr >= n) arr = n - 1;

    ushort4v a4;
    float4   af;

#define GLOADP(K0) {                                                                         \
        if constexpr (A_BF16)                                                                \
            a4 = *reinterpret_cast<const ushort4v*>(                                         \
                     (const ushort_t*)Av + (size_t)arr * DK + (K0) + ak);                    \
        else                                                                                 \
            af = *reinterpret_cast<const float4*>(                                           \
                     (const float*)Av + (size_t)arr * DK + (K0) + ak);                       \
    }
#define LSTOREP(BUF) {                                                                       \
        ushort4v ap;                                                                         \
        if constexpr (A_BF16) ap = a4;                                                       \
        else ap = (ushort4v){ f2bf(af.x), f2bf(af.y), f2bf(af.z), f2bf(af.w) };              \
        *reinterpret_cast<ushort4v*>(&As[BUF][ar * SA + ak]) = ap;                           \
    }

    GLOADP(0);
    LSTOREP(0);
    __syncthreads();
    int cur = 0;
#pragma unroll
    for (int s = 0; s < NS; ++s) {
        if (s + 1 < NS) GLOADP((s + 1) * BK);
        bf16x8 a0 = *reinterpret_cast<bf16x8*>(&As[cur][m * SA + quad * 8]);
        bf16x8 a1 = *reinterpret_cast<bf16x8*>(&As[cur][(16 + m) * SA + quad * 8]);
#pragma unroll
        for (int t = 0; t < NTW; ++t) {
            const ushort_t* wp =
                Wpk + (((size_t)(wv * NTW + t) * NS + s) * 64 + lane) * 8;
            bf16x8 b = *reinterpret_cast<const bf16x8*>(wp);
            acc[0][t] = __builtin_amdgcn_mfma_f32_16x16x32_bf16(a0, b, acc[0][t], 0, 0, 0);
            acc[1][t] = __builtin_amdgcn_mfma_f32_16x16x32_bf16(a1, b, acc[1][t], 0, 0, 0);
        }
        if (s + 1 < NS) {
            LSTOREP(cur ^ 1);
            __syncthreads();
            cur ^= 1;
        }
    }
#undef GLOADP
#undef LSTOREP

#pragma unroll
    for (int f = 0; f < 2; ++f) {
#pragma unroll
        for (int t = 0; t < NTW; ++t) {
#pragma unroll
            for (int i = 0; i < 4; ++i) {
                int r = row0 + f * 16 + quad * 4 + i;
                int c = cbase + t * 16 + m;
                if (r < n) {
                    if constexpr (OUT_FP8)
                        ((unsigned char*)Cv)[(size_t)r * DC + c] = f2fp8(acc[f][t][i]);
                    else
                        ((ushort_t*)Cv)[(size_t)r * DC + c] = f2bf(acc[f][t][i]);
                }
            }
        }
    }
}

// ---------------------------------------------------------------------------
// CSR SpMM, one wave per row, 4-way group edge parallelism; 16-edge main
// loop with 4 gathers in flight.  ep4 record loads are non-temporal
// (streamed once) and h/out stores are non-temporal, so the gather tables
// (sup1/sup2, 6.4MB each) keep L2 residency during the gather phase.
// NT ops use ext_vector types (clang builtin rejects HIP_vector_type).
// ---------------------------------------------------------------------------

__device__ __forceinline__ uint4v nt_load4(const unsigned* p) {
    return __builtin_nontemporal_load(reinterpret_cast<const uint4v*>(p));
}

// Layer 1: sup = fp8 e4m3 [n x 128], out h = bf16 [n x 128], bias + relu.
__global__ __launch_bounds__(256) void k_spmm1(const int2* __restrict__ rseg,
                                               const unsigned* __restrict__ ep4,
                                               const unsigned char* __restrict__ sup,
                                               const float* __restrict__ bias,
                                               ushort_t* __restrict__ h, int n) {
    const int w    = (blockIdx.x * 256 + threadIdx.x) >> 6;
    const int lane = threadIdx.x & 63;
    const int g    = lane >> 4;
    const int gl   = lane & 15;
    if (w >= n) return;
    const int2 seg = rseg[w];

    float a0 = 0.f, a1 = 0.f, a2 = 0.f, a3 = 0.f;
    float a4 = 0.f, a5 = 0.f, a6 = 0.f, a7 = 0.f;
    const int hoff = gl << 3;   // 8 fp8 dims per lane
    auto sel = [&](uint4v q) -> unsigned {
        unsigned r  = (g & 1) ? q.y : q.x;
        unsigned rr = (g & 1) ? q.w : q.z;
        return (g & 2) ? rr : r;
    };
    auto gld = [&](unsigned r) -> uint2 {
        return *reinterpret_cast<const uint2*>(
            sup + (((size_t)(r & 0xFFFFu)) << 7) + hoff);
    };
    auto acc8 = [&](unsigned r, uint2 v) {
        float ww = __half2float(__ushort_as_half((ushort_t)(r >> 16)));
        a0 = fmaf(ww, FP8CVT(v.x, 0), a0);
        a1 = fmaf(ww, FP8CVT(v.x, 1), a1);
        a2 = fmaf(ww, FP8CVT(v.x, 2), a2);
        a3 = fmaf(ww, FP8CVT(v.x, 3), a3);
        a4 = fmaf(ww, FP8CVT(v.y, 0), a4);
        a5 = fmaf(ww, FP8CVT(v.y, 1), a5);
        a6 = fmaf(ww, FP8CVT(v.y, 2), a6);
        a7 = fmaf(ww, FP8CVT(v.y, 3), a7);
    };
    int i = seg.x;
    for (; i + 16 <= seg.y; i += 16) {
        uint4v qa = nt_load4(ep4 + i);
        uint4v qb = nt_load4(ep4 + i + 4);
        uint4v qc = nt_load4(ep4 + i + 8);
        uint4v qd = nt_load4(ep4 + i + 12);
        unsigned r0 = sel(qa), r1 = sel(qb), r2 = sel(qc), r3 = sel(qd);
        uint2 v0 = gld(r0), v1 = gld(r1), v2 = gld(r2), v3 = gld(r3);
        acc8(r0, v0); acc8(r1, v1); acc8(r2, v2); acc8(r3, v3);
    }
    for (; i < seg.y; i += 8) {
        uint4v qa = nt_load4(ep4 + i);
        uint4v qb = nt_load4(ep4 + i + 4);
        unsigned r0 = sel(qa), r1 = sel(qb);
        uint2 v0 = gld(r0), v1 = gld(r1);
        acc8(r0, v0); acc8(r1, v1);
    }
    a0 += __shfl_xor(a0, 16); a0 += __shfl_xor(a0, 32);
    a1 += __shfl_xor(a1, 16); a1 += __shfl_xor(a1, 32);
    a2 += __shfl_xor(a2, 16); a2 += __shfl_xor(a2, 32);
    a3 += __shfl_xor(a3, 16); a3 += __shfl_xor(a3, 32);
    a4 += __shfl_xor(a4, 16); a4 += __shfl_xor(a4, 32);
    a5 += __shfl_xor(a5, 16); a5 += __shfl_xor(a5, 32);
    a6 += __shfl_xor(a6, 16); a6 += __shfl_xor(a6, 32);
    a7 += __shfl_xor(a7, 16); a7 += __shfl_xor(a7, 32);
    if (g == 0) {
        const int d = gl << 3;
        float4 bs0 = *reinterpret_cast<const float4*>(bias + d);
        float4 bs1 = *reinterpret_cast<const float4*>(bias + d + 4);
        a0 = fmaxf(a0 + bs0.x, 0.f); a1 = fmaxf(a1 + bs0.y, 0.f);
        a2 = fmaxf(a2 + bs0.z, 0.f); a3 = fmaxf(a3 + bs0.w, 0.f);
        a4 = fmaxf(a4 + bs1.x, 0.f); a5 = fmaxf(a5 + bs1.y, 0.f);
        a6 = fmaxf(a6 + bs1.z, 0.f); a7 = fmaxf(a7 + bs1.w, 0.f);
        uint4v pk;
        pk.x = (unsigned)f2bf(a0) | ((unsigned)f2bf(a1) << 16);
        pk.y = (unsigned)f2bf(a2) | ((unsigned)f2bf(a3) << 16);
        pk.z = (unsigned)f2bf(a4) | ((unsigned)f2bf(a5) << 16);
        pk.w = (unsigned)f2bf(a6) | ((unsigned)f2bf(a7) << 16);
        __builtin_nontemporal_store(pk,
            reinterpret_cast<uint4v*>(h + (size_t)w * HID_DIM + d));
    }
}

// Layer 2: sup = bf16 [n x 64], out = fp32 [n x 64], bias, no relu.
__global__ __launch_bounds__(256) void k_spmm2(const int2* __restrict__ rseg,
                                               const unsigned* __restrict__ ep4,
                                               const ushort_t* __restrict__ sup,
                                               const float* __restrict__ bias,
                                               float* __restrict__ out, int n) {
    const int w    = (blockIdx.x * 256 + threadIdx.x) >> 6;
    const int lane = threadIdx.x & 63;
    const int g    = lane >> 4;
    const int gl   = lane & 15;
    if (w >= n) return;
    const int2 seg = rseg[w];

    float a0 = 0.f, a1 = 0.f, a2 = 0.f, a3 = 0.f;
    const unsigned char* supb = (const unsigned char*)sup;
    const int hoff = gl << 3;   // 4 bf16 dims per lane
    auto sel = [&](uint4v q) -> unsigned {
        unsigned r  = (g & 1) ? q.y : q.x;
        unsigned rr = (g & 1) ? q.w : q.z;
        return (g & 2) ? rr : r;
    };
    auto gld = [&](unsigned r) -> uint2 {
        return *reinterpret_cast<const uint2*>(
            supb + (((size_t)(r & 0xFFFFu)) << 7) + hoff);
    };
    auto acc4 = [&](unsigned r, uint2 v) {
        float ww = __half2float(__ushort_as_half((ushort_t)(r >> 16)));
        a0 = fmaf(ww, __uint_as_float(v.x << 16), a0);
        a1 = fmaf(ww, __uint_as_float(v.x & 0xFFFF0000u), a1);
        a2 = fmaf(ww, __uint_as_float(v.y << 16), a2);
        a3 = fmaf(ww, __uint_as_float(v.y & 0xFFFF0000u), a3);
    };
    int i = seg.x;
    for (; i + 16 <= seg.y; i += 16) {
        uint4v qa = nt_load4(ep4 + i);
        uint4v qb = nt_load4(ep4 + i + 4);
        uint4v qc = nt_load4(ep4 + i + 8);
        uint4v qd = nt_load4(ep4 + i + 12);
        unsigned r0 = sel(qa), r1 = sel(qb), r2 = sel(qc), r3 = sel(qd);
        uint2 v0 = gld(r0), v1 = gld(r1), v2 = gld(r2), v3 = gld(r3);
        acc4(r0, v0); acc4(r1, v1); acc4(r2, v2); acc4(r3, v3);
    }
    for (; i < seg.y; i += 8) {
        uint4v qa = nt_load4(ep4 + i);
        uint4v qb = nt_load4(ep4 + i + 4);
        unsigned r0 = sel(qa), r1 = sel(qb);
        uint2 v0 = gld(r0), v1 = gld(r1);
        acc4(r0, v0); acc4(r1, v1);
    }
    a0 += __shfl_xor(a0, 16); a0 += __shfl_xor(a0, 32);
    a1 += __shfl_xor(a1, 16); a1 += __shfl_xor(a1, 32);
    a2 += __shfl_xor(a2, 16); a2 += __shfl_xor(a2, 32);
    a3 += __shfl_xor(a3, 16); a3 += __shfl_xor(a3, 32);
    if (g == 0) {
        const int d = gl << 2;
        float4 bs = *reinterpret_cast<const float4*>(bias + d);
        floatx4 o = (floatx4){a0 + bs.x, a1 + bs.y, a2 + bs.z, a3 + bs.w};
        __builtin_nontemporal_store(o,
            reinterpret_cast<floatx4*>(out + (size_t)w * OUT_DIM + d));
    }
}

// Legacy SpMM (8-byte int2 records, fp32 weights) — fallback path only.
template <int D, bool RELU, bool OUT_BF16, bool SUP_FP8>
__global__ __launch_bounds__(256) void k_spmm_legacy(const int* __restrict__ rp,
                                                     const int2* __restrict__ ep,
                                                     const void* __restrict__ supv,
                                                     const float* __restrict__ bias,
                                                     void* __restrict__ outv, int n) {
    const int w    = (blockIdx.x * 256 + threadIdx.x) >> 6;
    const int lane = threadIdx.x & 63;
    if (w >= n) return;
    const int s = rp[w], e = rp[w + 1];

    if constexpr (D == 128) {
        const int d = lane * 2;
        float accx = 0.f, accy = 0.f;
        for (int i = s; i < e; ++i) {
            int2 r = ep[i];
            float ww = __int_as_float(r.y);
            if constexpr (SUP_FP8) {
                const unsigned char* sup = (const unsigned char*)supv;
                unsigned short u = *reinterpret_cast<const unsigned short*>(&sup[(size_t)r.x * D + d]);
                accx = fmaf(ww, fp82f((unsigned char)(u & 255)), accx);
                accy = fmaf(ww, fp82f((unsigned char)(u >> 8)), accy);
            } else {
                const ushort_t* sup = (const ushort_t*)supv;
                unsigned u = *reinterpret_cast<const unsigned*>(&sup[(size_t)r.x * D + d]);
                accx = fmaf(ww, __uint_as_float(u << 16), accx);
                accy = fmaf(ww, __uint_as_float(u & 0xFFFF0000u), accy);
            }
        }
        accx += bias[d]; accy += bias[d + 1];
        if (RELU) { accx = fmaxf(accx, 0.f); accy = fmaxf(accy, 0.f); }
        if constexpr (OUT_BF16) {
            unsigned pk = (unsigned)f2bf(accx) | ((unsigned)f2bf(accy) << 16);
            *reinterpret_cast<unsigned*>((ushort_t*)outv + (size_t)w * D + d) = pk;
        } else {
            *reinterpret_cast<float2*>((float*)outv + (size_t)w * D + d) =
                make_float2(accx, accy);
        }
    } else {
        const int d = lane;
        const ushort_t* sup = (const ushort_t*)supv;
        float acc = 0.f;
        for (int i = s; i < e; ++i) {
            int2 r = ep[i];
            acc = fmaf(__int_as_float(r.y), bf2f(sup[(size_t)r.x * D + d]), acc);
        }
        acc += bias[d];
        if (RELU) acc = fmaxf(acc, 0.f);
        if constexpr (OUT_BF16)
            ((ushort_t*)outv)[(size_t)w * D + d] = f2bf(acc);
        else
            ((float*)outv)[(size_t)w * D + d] = acc;
    }
}

// ---------------------------------------------------------------------------

extern "C" void kernel_launch(void* const* d_in, const int* in_sizes, int n_in,
                              void* d_out, int out_size, void* d_ws, size_t ws_size,
                              hipStream_t stream) {
    const float* x  = (const float*)d_in[0];
    const int*   ei = (const int*)d_in[1];
    const float* ew = (const float*)d_in[2];
    const float* W1 = (const float*)d_in[3];
    const float* b1 = (const float*)d_in[4];
    const float* W2 = (const float*)d_in[5];
    const float* b2 = (const float*)d_in[6];
    float* out = (float*)d_out;

    const int n = in_sizes[0] / IN_DIM;  // 50000
    const int E = in_sizes[2];           // 1600000
    const int* rows = ei;
    const int* cols = ei + E;

    char* ws = (char*)d_ws;
    size_t off = 0;
    auto alloc = [&](size_t bytes) -> void* {
        off = (off + 255) & ~(size_t)255;
        void* p = ws + off;
        off += bytes;
        return p;
    };
    // padded edge capacity: E + per-bucket slack
    const size_t epad = (size_t)E + (size_t)NBMAX * BSLACK;
    unsigned* ep4     = (unsigned*)alloc(epad * sizeof(unsigned));
    int2*     rseg    = (int2*)alloc((size_t)n * sizeof(int2));
    int*      bcnt    = (int*)alloc(NBMAX * sizeof(int));
    int*      bbase   = (int*)alloc((NBMAX + 1) * sizeof(int));
    int*      bfill   = (int*)alloc(NBMAX * sizeof(int));
    int*      done    = (int*)alloc(256);
    ushort_t* Wt1     = (ushort_t*)alloc((size_t)IN_DIM * HID_DIM * sizeof(ushort_t));
    ushort_t* Wpk2    = (ushort_t*)alloc((size_t)NE2 * 8 * sizeof(ushort_t));
    // shared region: ept (bin temp, epad*8B) | sup1 (n*128 fp8) | sup2 (n*64 bf16)
    size_t sup1_bytes = (size_t)n * HID_DIM;
    size_t sup2_bytes = (size_t)n * OUT_DIM * sizeof(ushort_t);
    size_t ept_bytes  = epad * sizeof(int2);
    size_t reg = sup1_bytes > ept_bytes ? sup1_bytes : ept_bytes;
    if (sup2_bytes > reg) reg = sup2_bytes;
    unsigned char* sup1 = (unsigned char*)alloc(reg);
    ushort_t* h    = (ushort_t*)alloc((size_t)n * HID_DIM * sizeof(ushort_t));
    ushort_t* sup2 = (ushort_t*)sup1;  // sup1 dead after spmm1
    int2*     ept  = (int2*)sup1;      // bin temp aliases sup1 (dead until gemm1)

    const int nbk  = (n + 127) / 128;
    const int nbh  = (E + BH_TILE - 1) / BH_TILE;
    const int binb = (E + BIN_TILE - 1) / BIN_TILE;
    const int gemb = (n + 127) / 128;
    const int pkb  = (n + 31) / 32;
    const int wb   = (IN_DIM * HID_DIM + NE2 + 255) / 256;

    // 1. weight prep (W1 transpose + W2 frag-pack) + zero bcnt/done
    k_wcvt2<<<wb, 256, 0, stream>>>(W1, Wt1, W2, Wpk2, bcnt, done);

    if (n <= 65536) {
        // 2. bucket hist + in-kernel scan (last-block pattern)
        k_bhist2<<<nbh, 256, 0, stream>>>(rows, bcnt, bbase, bfill, done, E, nbk, nbh);
        // 3-4. bin -> unbin
        k_bin<<<binb, 256, 0, stream>>>(rows, cols, ew, bfill, ept, E, nbk);
        k_unbin<<<nbk, 256, 0, stream>>>(bbase, bcnt, ept, ep4, rseg, n);
        // 5. gemm1 (BR=128): x @ W1 -> fp8 sup1
        k_gemm_mfma<IN_DIM, HID_DIM, false, true><<<gemb, 256, 0, stream>>>(x, Wt1, sup1, n);
        // 6. spmm1 (4-gather MLP, NT streams) -> h bf16
        k_spmm1<<<(n + 3) / 4, 256, 0, stream>>>(rseg, ep4, sup1, b1, h, n);
        // 7. gemm2 (packed-W): h @ W2 -> bf16 sup2
        k_gemm_pk<HID_DIM, OUT_DIM, true, false><<<pkb, 256, 0, stream>>>(h, Wpk2, sup2, n);
        // 8. spmm2 (4-gather MLP, NT streams) -> out
        k_spmm2<<<(n + 3) / 4, 256, 0, stream>>>(rseg, ep4, sup2, b2, out, n);
    } else {
        // --- fallback: row-level hist -> scan -> direct scatter (8B recs) ---
        int*  row_ptr  = (int*)alloc((size_t)(n + 1) * sizeof(int));
        int*  deg      = (int*)alloc((size_t)n * sizeof(int));
        int*  row_fill = (int*)alloc((size_t)n * sizeof(int));
        int*  bsum     = (int*)alloc(256 * sizeof(int));
        int*  bscn     = (int*)alloc(256 * sizeof(int));
        int2* ep8      = (int2*)alloc((size_t)E * sizeof(int2));
        const int nb = (n + SCAN_TILE - 1) / SCAN_TILE;
        k_zero<<<(n + 255) / 256, 256, 0, stream>>>(deg, n);
        k_hist<<<(E + 255) / 256, 256, 0, stream>>>(rows, deg, E);
        k_scan1<<<nb, 256, 0, stream>>>(deg, bsum, n);
        k_scan2<<<1, 256, 0, stream>>>(bsum, bscn, nb);
        k_scan3<<<nb, 256, 0, stream>>>(deg, bscn, row_ptr, row_fill, n, E);
        k_scatter<<<(E + 255) / 256, 256, 0, stream>>>(rows, cols, ew, row_fill, ep8, E);

        k_gemm_mfma<IN_DIM, HID_DIM, false, true><<<gemb, 256, 0, stream>>>(x, Wt1, sup1, n);
        k_spmm_legacy<HID_DIM, true, true, true><<<(n + 3) / 4, 256, 0, stream>>>(row_ptr, ep8, sup1, b1, h, n);
        k_gemm_pk<HID_DIM, OUT_DIM, true, false><<<pkb, 256, 0, stream>>>(h, Wpk2, (void*)sup2, n);
        k_spmm_legacy<OUT_DIM, false, false, false><<<(n + 3) / 4, 256, 0, stream>>>(row_ptr, ep8, sup2, b2, out, n);
    }
}

// Round 13
// 316.097 us; speedup vs baseline: 1.0305x; 1.0305x over previous
//
#include <hip/hip_runtime.h>
#include <hip/hip_fp8.h>
#include <hip/hip_fp16.h>

// Problem constants: N=50000, E=1.6M, dims 512 -> 128 -> 64
#define IN_DIM  512
#define HID_DIM 128
#define OUT_DIM 64

typedef unsigned short ushort_t;
typedef ushort_t ushort4v __attribute__((ext_vector_type(4)));
typedef ushort_t ushort8 __attribute__((ext_vector_type(8)));
typedef __bf16  bf16x8  __attribute__((ext_vector_type(8)));
typedef float   floatx4 __attribute__((ext_vector_type(4)));

// fp32 -> bf16 round-to-nearest-even (bit trick; inputs are finite)
__device__ __forceinline__ ushort_t f2bf(float f) {
    union { float f; unsigned u; } v; v.f = f;
    unsigned r = v.u + 0x7FFFu + ((v.u >> 16) & 1u);
    return (ushort_t)(r >> 16);
}
__device__ __forceinline__ float bf2f(ushort_t u) {
    return __uint_as_float(((unsigned)u) << 16);
}
// fp32 <-> fp8 e4m3 (OCP fn) via HIP type (HW v_cvt on gfx950)
__device__ __forceinline__ unsigned char f2fp8(float f) {
    __hip_fp8_e4m3 t(f); return (unsigned char)t.__x;
}
__device__ __forceinline__ float fp82f(unsigned char b) {
    __hip_fp8_e4m3 t; t.__x = (__hip_fp8_storage_t)b; return (float)t;
}
// direct byte-select fp8->f32 (1 VALU op on gfx950); fallback = extract+cvt
#if __has_builtin(__builtin_amdgcn_cvt_f32_fp8)
#define FP8CVT(v, j) __builtin_amdgcn_cvt_f32_fp8((v), (j))
#else
#define FP8CVT(v, j) fp82f((unsigned char)(((v) >> ((j) * 8)) & 255u))
#endif

__global__ void k_zero(int* __restrict__ p, int n) {
    int i = blockIdx.x * blockDim.x + threadIdx.x;
    if (i < n) p[i] = 0;
}

// ---------------------------------------------------------------------------
// Pipeline (main path, 8 dispatches; exact R9 structure = best measured
// 316.6us across 13 configurations; NT-hint variant (R12) regressed +9us
// because nt bypasses L2: ep4 stream lost L2 prefetch locality and the NT
// h-store evicted gemm2's input):
//   k_wcvt2  : W1 transpose (bf16) + W2 pack (MFMA-frag order) + zero bcnt/done
//   k_bhist2 : bucket histogram; LAST finishing block runs the scan in-kernel
//   k_bin    : LDS-staged binning into bucket regions (ept)
//   k_unbin  : per-bucket scatter to final padded 4B records + rseg
//   k_gemm   : x @ W1  (BR=128 LDS double-buffered MFMA — best measured;
//              packed-W variants BR=32/BR=64 both regressed, R8/R10)
//   k_spmm1  : spmm layer1 (fp8 gather, 4-gathers-in-flight) -> h bf16
//   k_gemm_pk: h @ W2  (BR=32 packed-W, R9-proven)
//   k_spmm2  : spmm layer2 -> out
// Edge record: {col:16 | fp16 weight:16}; row segments padded to 8 records.
// ---------------------------------------------------------------------------

#define BIN_TILE 4096
#define BH_TILE  8192
#define NBMAX    512
// per-bucket slack for per-row pad-to-8 (<=128*7=896) + base 8-alignment
#define BSLACK   1032
// k_unbin LDS staging capacity; larger buckets spill to global reads
#define UNBIN_LDS 8192
// packed-W2 entries: (OUT/16 tiles) * (HID/32 steps) * 64 lanes
#define NE2 ((OUT_DIM / 16) * (HID_DIM / 32) * 64)   // 1024

// --- wcvt2: W1 transpose + W2 MFMA-frag pack + zero bcnt/done --------------
__global__ void k_wcvt2(const float* __restrict__ W1, ushort_t* __restrict__ Wt1,
                        const float* __restrict__ W2, ushort_t* __restrict__ Wpk2,
                        int* __restrict__ bcnt, int* __restrict__ done) {
    if (blockIdx.x == 0) {
        bcnt[threadIdx.x] = 0;
        bcnt[threadIdx.x + 256] = 0;
        if (threadIdx.x == 0) *done = 0;
    }
    int i = blockIdx.x * blockDim.x + threadIdx.x;
    if (i < IN_DIM * HID_DIM) {
        int k = i / HID_DIM, c = i % HID_DIM;
        Wt1[(size_t)c * IN_DIM + k] = f2bf(W1[i]);
    } else {
        int q = i - IN_DIM * HID_DIM;
        if (q < NE2) {
            int l = q & 63, rest = q >> 6;
            int s  = rest & (HID_DIM / 32 - 1);   // 0..3
            int tt = rest >> 2;                   // 0..3
            int col  = tt * 16 + (l & 15);
            int krow = s * 32 + ((l >> 4) << 3);
            ushort8 v;
#pragma unroll
            for (int j = 0; j < 8; ++j)
                v[j] = f2bf(W2[(size_t)(krow + j) * OUT_DIM + col]);
            *reinterpret_cast<ushort8*>(Wpk2 + (size_t)q * 8) = v;
        }
    }
}

// --- bhist2: LDS-privatized bucket histogram -> global atomics; the LAST
// block to finish (atomic done counter) performs the exclusive scan of
// padded counts in-kernel.  No spinning: deadlock-free by construction.
__global__ __launch_bounds__(256) void k_bhist2(const int* __restrict__ rows,
                                                int* __restrict__ bcnt,
                                                int* __restrict__ bucket_base,
                                                int* __restrict__ bucket_fill,
                                                int* __restrict__ done,
                                                int E, int nbk, int nblk) {
    __shared__ int lc[NBMAX];
    __shared__ int amLast;
    const int t = threadIdx.x;
    lc[t] = 0; lc[t + 256] = 0;
    __syncthreads();
    const int base = blockIdx.x * BH_TILE;
#pragma unroll
    for (int j = 0; j < BH_TILE / 256; ++j) {
        int e = base + t + j * 256;
        if (e < E) atomicAdd(&lc[rows[e] >> 7], 1);
    }
    __syncthreads();
    if (lc[t])       atomicAdd(&bcnt[t], lc[t]);
    if (lc[t + 256]) atomicAdd(&bcnt[t + 256], lc[t + 256]);
    __syncthreads();   // each wave drains its vmem (incl. atomics) here
    if (t == 0) {
        __threadfence();
        amLast = (atomicAdd(done, 1) == nblk - 1) ? 1 : 0;
    }
    __syncthreads();
    if (!amLast) return;

    // final block: device-scope atomic reads of the complete histogram
    int c0 = atomicAdd(&bcnt[t], 0);
    int c1 = atomicAdd(&bcnt[t + 256], 0);
    lc[t]       = (t < nbk)       ? (((c0 + 7) & ~7) + 1024) : 0;
    lc[t + 256] = (t + 256 < nbk) ? (((c1 + 7) & ~7) + 1024) : 0;
    __syncthreads();
    for (int d = 1; d < NBMAX; d <<= 1) {
        int v0 = (t >= d) ? lc[t - d] : 0;
        int v1 = (t + 256 >= d) ? lc[t + 256 - d] : 0;
        __syncthreads();
        lc[t] += v0; lc[t + 256] += v1;
        __syncthreads();
    }
#pragma unroll
    for (int l = 0; l < 2; ++l) {
        int i = t + l * 256;
        if (i < nbk) {
            int v = (i == 0) ? 0 : lc[i - 1];
            bucket_base[i] = v;
            bucket_fill[i] = v;
        }
    }
}

// Phase A: bin edges into bucket regions of ept with LDS staging.
// Record: .x = col | rowoff<<16 | bucket<<23, .y = fp16(weight) << 16.
__global__ __launch_bounds__(256) void k_bin(const int* __restrict__ rows,
                                             const int* __restrict__ cols,
                                             const float* __restrict__ ew,
                                             int* __restrict__ bucket_fill,
                                             int2* __restrict__ ept, int E, int nbk) {
    __shared__ int cnt[NBMAX], inc[NBMAX], cnt2[NBMAX], gbase[NBMAX];
    __shared__ int2 stage[BIN_TILE];
    const int t = threadIdx.x;
    const int tile0 = blockIdx.x * BIN_TILE;

    cnt[t] = 0; cnt[t + 256] = 0; cnt2[t] = 0; cnt2[t + 256] = 0;
    __syncthreads();

    int px[16], pw[16];
    int nv = 0;
#pragma unroll
    for (int j = 0; j < 16; ++j) {
        int e = tile0 + t + j * 256;
        if (e < E) {
            int r = rows[e];
            int b = r >> 7;
            px[nv] = cols[e] | ((r & 127) << 16) | (b << 23);
            pw[nv] = ((int)__half_as_ushort(__float2half(ew[e]))) << 16;
            ++nv;
            atomicAdd(&cnt[b], 1);
        }
    }
    __syncthreads();

    inc[t] = cnt[t]; inc[t + 256] = cnt[t + 256];
    __syncthreads();
    for (int d = 1; d < NBMAX; d <<= 1) {
        int v0 = (t >= d) ? inc[t - d] : 0;
        int v1 = (t + 256 >= d) ? inc[t + 256 - d] : 0;
        __syncthreads();
        inc[t] += v0; inc[t + 256] += v1;
        __syncthreads();
    }

    if (t < nbk && cnt[t] > 0)             gbase[t]       = atomicAdd(&bucket_fill[t], cnt[t]);
    if (t + 256 < nbk && cnt[t + 256] > 0) gbase[t + 256] = atomicAdd(&bucket_fill[t + 256], cnt[t + 256]);

    for (int j = 0; j < nv; ++j) {
        int b = ((unsigned)px[j]) >> 23;
        int off = (b == 0) ? 0 : inc[b - 1];
        int r = atomicAdd(&cnt2[b], 1);
        stage[off + r] = make_int2(px[j], pw[j]);
    }
    __syncthreads();

    int total = inc[nbk - 1];
    for (int s = t; s < total; s += 256) {
        int2 rec = stage[s];
        int b = ((unsigned)rec.x) >> 23;
        int off = (b == 0) ? 0 : inc[b - 1];
        ept[gbase[b] + (s - off)] = rec;
    }
}

// Phase B: one block per bucket; stages the bucket's records in LDS (single
// global read of ept), derives padded per-row segments rseg[r], scatters
// 4-byte records from LDS; pads with w=0.  Buckets > UNBIN_LDS spill.
__global__ __launch_bounds__(256) void k_unbin(const int* __restrict__ bucket_base,
                                               const int* __restrict__ bcnt,
                                               const int2* __restrict__ ept,
                                               unsigned* __restrict__ ep4,
                                               int2* __restrict__ rseg,
                                               int n) {
    __shared__ int rcnt[128], sc[128], fill[128], rbase[128];
    __shared__ int2 lrec[UNBIN_LDS];
    const int b = blockIdx.x;
    const int t = threadIdx.x;
    const int r0 = b << 7;
    const int nrows = (n - r0 < 128) ? (n - r0) : 128;
    const int bstart = bucket_base[b];
    const int cnt    = bcnt[b];
    const int inl    = (cnt < UNBIN_LDS) ? cnt : UNBIN_LDS;

    if (t < 128) rcnt[t] = 0;
    __syncthreads();

    for (int e = t; e < inl; e += 256) {
        int2 rec = ept[bstart + e];
        lrec[e] = rec;
        atomicAdd(&rcnt[(rec.x >> 16) & 127], 1);
    }
    for (int e = inl + t; e < cnt; e += 256)
        atomicAdd(&rcnt[(ept[bstart + e].x >> 16) & 127], 1);
    __syncthreads();

    if (t < 128) sc[t] = (rcnt[t] + 7) & ~7;   // padded per-row counts
    __syncthreads();
    for (int d = 1; d < 128; d <<= 1) {
        int v = (t >= d && t < 128) ? sc[t - d] : 0;
        __syncthreads();
        if (t < 128) sc[t] += v;
        __syncthreads();
    }
    if (t < 128) {
        int start = bstart + ((t == 0) ? 0 : sc[t - 1]);
        rbase[t] = start;
        fill[t]  = start;
        if (t < nrows)
            rseg[r0 + t] = make_int2(start, start + ((rcnt[t] + 7) & ~7));
    }
    __syncthreads();

    for (int e = t; e < inl; e += 256) {
        int2 rec = lrec[e];
        int ro = (rec.x >> 16) & 127;
        int p = atomicAdd(&fill[ro], 1);
        ep4[p] = ((unsigned)rec.x & 0xFFFFu) | ((unsigned)rec.y & 0xFFFF0000u);
    }
    for (int e = inl + t; e < cnt; e += 256) {
        int2 rec = ept[bstart + e];
        int ro = (rec.x >> 16) & 127;
        int p = atomicAdd(&fill[ro], 1);
        ep4[p] = ((unsigned)rec.x & 0xFFFFu) | ((unsigned)rec.y & 0xFFFF0000u);
    }
    __syncthreads();

    if (t < 128) {
        int pend = rbase[t] + ((rcnt[t] + 7) & ~7);
        for (int p = fill[t]; p < pend; ++p) ep4[p] = 0u;  // col 0, w = 0
    }
}

// --- fallback CSR build for n > 65536: hist -> 3-kernel scan -> scatter ----

__global__ void k_hist(const int* __restrict__ rows, int* __restrict__ deg, int E) {
    int i = blockIdx.x * blockDim.x + threadIdx.x;
    if (i < E) atomicAdd(&deg[rows[i]], 1);
}

#define SCAN_TILE 2048

__global__ __launch_bounds__(256) void k_scan1(const int* __restrict__ deg,
                                               int* __restrict__ bsum, int n) {
    __shared__ int s[256];
    const int tid = threadIdx.x;
    const int base = blockIdx.x * SCAN_TILE + tid * 8;
    int sum = 0;
#pragma unroll
    for (int i = 0; i < 8; ++i) { int idx = base + i; if (idx < n) sum += deg[idx]; }
    s[tid] = sum;
    __syncthreads();
#pragma unroll
    for (int off = 128; off > 0; off >>= 1) {
        if (tid < off) s[tid] += s[tid + off];
        __syncthreads();
    }
    if (tid == 0) bsum[blockIdx.x] = s[0];
}

__global__ __launch_bounds__(256) void k_scan2(const int* __restrict__ bsum,
                                               int* __restrict__ bscan, int nb) {
    __shared__ int s[256];
    const int tid = threadIdx.x;
    s[tid] = (tid < nb) ? bsum[tid] : 0;
    __syncthreads();
#pragma unroll
    for (int off = 1; off < 256; off <<= 1) {
        int v = (tid >= off) ? s[tid - off] : 0;
        __syncthreads();
        s[tid] += v;
        __syncthreads();
    }
    if (tid < nb) bscan[tid] = (tid == 0) ? 0 : s[tid - 1];
}

__global__ __launch_bounds__(256) void k_scan3(const int* __restrict__ deg,
                                               const int* __restrict__ bscan,
                                               int* __restrict__ row_ptr,
                                               int* __restrict__ row_fill,
                                               int n, int E) {
    __shared__ int s[256];
    const int tid = threadIdx.x;
    const int base = blockIdx.x * SCAN_TILE + tid * 8;
    int v[8];
#pragma unroll
    for (int i = 0; i < 8; ++i) { int idx = base + i; v[i] = (idx < n) ? deg[idx] : 0; }
    int sum = 0;
#pragma unroll
    for (int i = 0; i < 8; ++i) sum += v[i];
    s[tid] = sum;
    __syncthreads();
#pragma unroll
    for (int off = 1; off < 256; off <<= 1) {
        int t = (tid >= off) ? s[tid - off] : 0;
        __syncthreads();
        s[tid] += t;
        __syncthreads();
    }
    int run = bscan[blockIdx.x] + ((tid == 0) ? 0 : s[tid - 1]);
#pragma unroll
    for (int i = 0; i < 8; ++i) {
        int idx = base + i;
        if (idx < n) {
            row_ptr[idx]  = run;
            row_fill[idx] = run;
            run += v[i];
        }
    }
    if (blockIdx.x == 0 && tid == 0) row_ptr[n] = E;
}

__global__ void k_scatter(const int* __restrict__ rows, const int* __restrict__ cols,
                          const float* __restrict__ ew, int* __restrict__ row_fill,
                          int2* __restrict__ ep, int E) {
    int i = blockIdx.x * blockDim.x + threadIdx.x;
    if (i < E) {
        int r = rows[i];
        int p = atomicAdd(&row_fill[r], 1);
        ep[p] = make_int2(cols[i], __float_as_int(ew[i]));
    }
}

// ---------------------------------------------------------------------------
// MFMA bf16 GEMM, BR=128, LDS double-buffered, one barrier per K-step.
// (Best measured structure for the tall gemm1 across BR=32/64/128 trials.)
// ---------------------------------------------------------------------------
template <int DK, int DC, bool A_BF16, bool OUT_FP8>
__global__ __launch_bounds__(256) void k_gemm_mfma(const void* __restrict__ Av,
                                                   const ushort_t* __restrict__ Wt,
                                                   void* __restrict__ Cv, int n) {
    constexpr int BR = 128, BK = 32, NT = DC / 16, SA = 40;
    __shared__ __align__(16) ushort_t As[2][BR * SA];
    __shared__ __align__(16) ushort_t Ws[2][DC * SA];

    const int tid  = threadIdx.x;
    const int wv   = tid >> 6;
    const int lane = tid & 63;
    const int m    = lane & 15;
    const int quad = lane >> 4;
    const int row0 = blockIdx.x * BR;

    floatx4 acc[2][NT];
#pragma unroll
    for (int f = 0; f < 2; ++f)
#pragma unroll
        for (int t = 0; t < NT; ++t) acc[f][t] = (floatx4){0.f, 0.f, 0.f, 0.f};

    const int ar = tid >> 1;
    const int ak = (tid & 1) * 16;
    int arr = row0 + ar; if (arr >= n) arr = n - 1;
    const int wc = (DC == 128) ? (tid >> 1) : (tid >> 2);
    const int wk = (DC == 128) ? ((tid & 1) * 16) : ((tid & 3) * 8);

    float4 af0, af1, af2, af3;
    ushort8 ab0, ab1;
    ushort8 wr0, wr1;

#define GLOAD(K0) {                                                                          \
        if constexpr (A_BF16) {                                                              \
            const ushort_t* Ab = (const ushort_t*)Av + (size_t)arr * DK + (K0) + ak;         \
            ab0 = *reinterpret_cast<const ushort8*>(Ab);                                     \
            ab1 = *reinterpret_cast<const ushort8*>(Ab + 8);                                 \
        } else {                                                                             \
            const float* Ab = (const float*)Av + (size_t)arr * DK + (K0) + ak;               \
            af0 = *reinterpret_cast<const float4*>(Ab);                                      \
            af1 = *reinterpret_cast<const float4*>(Ab + 4);                                  \
            af2 = *reinterpret_cast<const float4*>(Ab + 8);                                  \
            af3 = *reinterpret_cast<const float4*>(Ab + 12);                                 \
        }                                                                                    \
        wr0 = *reinterpret_cast<const ushort8*>(&Wt[(size_t)wc * DK + (K0) + wk]);           \
        if constexpr (DC == 128)                                                             \
            wr1 = *reinterpret_cast<const ushort8*>(&Wt[(size_t)wc * DK + (K0) + wk + 8]);   \
    }
#define LSTORE(BUF) {                                                                        \
        ushort8 ap0, ap1;                                                                    \
        if constexpr (A_BF16) { ap0 = ab0; ap1 = ab1; }                                      \
        else {                                                                               \
            ap0 = (ushort8){ f2bf(af0.x), f2bf(af0.y), f2bf(af0.z), f2bf(af0.w),             \
                             f2bf(af1.x), f2bf(af1.y), f2bf(af1.z), f2bf(af1.w) };           \
            ap1 = (ushort8){ f2bf(af2.x), f2bf(af2.y), f2bf(af2.z), f2bf(af2.w),             \
                             f2bf(af3.x), f2bf(af3.y), f2bf(af3.z), f2bf(af3.w) };           \
        }                                                                                    \
        *reinterpret_cast<ushort8*>(&As[BUF][ar * SA + ak])     = ap0;                       \
        *reinterpret_cast<ushort8*>(&As[BUF][ar * SA + ak + 8]) = ap1;                       \
        *reinterpret_cast<ushort8*>(&Ws[BUF][wc * SA + wk]) = wr0;                           \
        if constexpr (DC == 128)                                                             \
            *reinterpret_cast<ushort8*>(&Ws[BUF][wc * SA + wk + 8]) = wr1;                   \
    }

    GLOAD(0);
    LSTORE(0);
    __syncthreads();
    int cur = 0;
#pragma unroll
    for (int k0 = 0; k0 < DK; k0 += BK) {
        const int nxt = k0 + BK;
        if (nxt < DK) GLOAD(nxt);
        bf16x8 a0 = *reinterpret_cast<bf16x8*>(&As[cur][(wv * 32 + m) * SA + quad * 8]);
        bf16x8 a1 = *reinterpret_cast<bf16x8*>(&As[cur][(wv * 32 + 16 + m) * SA + quad * 8]);
#pragma unroll
        for (int t = 0; t < NT; ++t) {
            bf16x8 bfr = *reinterpret_cast<bf16x8*>(&Ws[cur][(t * 16 + m) * SA + quad * 8]);
            acc[0][t] = __builtin_amdgcn_mfma_f32_16x16x32_bf16(a0, bfr, acc[0][t], 0, 0, 0);
            acc[1][t] = __builtin_amdgcn_mfma_f32_16x16x32_bf16(a1, bfr, acc[1][t], 0, 0, 0);
        }
        if (nxt < DK) {
            LSTORE(cur ^ 1);
            __syncthreads();
            cur ^= 1;
        }
    }
#undef GLOAD
#undef LSTORE

#pragma unroll
    for (int f = 0; f < 2; ++f) {
#pragma unroll
        for (int t = 0; t < NT; ++t) {
#pragma unroll
            for (int i = 0; i < 4; ++i) {
                int r = row0 + wv * 32 + f * 16 + quad * 4 + i;
                if (r < n) {
                    if constexpr (OUT_FP8)
                        ((unsigned char*)Cv)[(size_t)r * DC + t * 16 + m] = f2fp8(acc[f][t][i]);
                    else
                        ((ushort_t*)Cv)[(size_t)r * DC + t * 16 + m] = f2bf(acc[f][t][i]);
                }
            }
        }
    }
}

// ---------------------------------------------------------------------------
// Packed-W MFMA GEMM (R9-proven): BR=32, wave owns DC/4 cols, A-only 5KB LDS.
// Used for the small gemm2 (DC=64).
// ---------------------------------------------------------------------------
template <int DK, int DC, bool A_BF16, bool OUT_FP8>
__global__ __launch_bounds__(256) void k_gemm_pk(const void* __restrict__ Av,
                                                 const ushort_t* __restrict__ Wpk,
                                                 void* __restrict__ Cv, int n) {
    constexpr int BR = 32, BK = 32, SA = 40;
    constexpr int NTW = DC / 64;
    constexpr int NS  = DK / 32;
    __shared__ __align__(16) ushort_t As[2][BR * SA];

    const int tid  = threadIdx.x;
    const int wv   = tid >> 6;
    const int lane = tid & 63;
    const int m    = lane & 15;
    const int quad = lane >> 4;
    const int row0 = blockIdx.x * BR;
    const int cbase = wv * (DC / 4);

    floatx4 acc[2][NTW];
#pragma unroll
    for (int f = 0; f < 2; ++f)
#pragma unroll
        for (int t = 0; t < NTW; ++t) acc[f][t] = (floatx4){0.f, 0.f, 0.f, 0.f};

    const int ar = tid >> 3;
    const int ak = (tid & 7) * 4;
    int arr = row0 + ar; if (arr >= n) arr = n - 1;

    ushort4v a4;
    float4   af;

#define GLOADP(K0) {                                                                         \
        if constexpr (A_BF16)                                                                \
            a4 = *reinterpret_cast<const ushort4v*>(                                         \
                     (const ushort_t*)Av + (size_t)arr * DK + (K0) + ak);                    \
        else                                                                                 \
            af = *reinterpret_cast<const float4*>(                                           \
                     (const float*)Av + (size_t)arr * DK + (K0) + ak);                       \
    }
#define LSTOREP(BUF) {                                                                       \
        ushort4v ap;                                                                         \
        if constexpr (A_BF16) ap = a4;                                                       \
        else ap = (ushort4v){ f2bf(af.x), f2bf(af.y), f2bf(af.z), f2bf(af.w) };              \
        *reinterpret_cast<ushort4v*>(&As[BUF][ar * SA + ak]) = ap;                           \
    }

    GLOADP(0);
    LSTOREP(0);
    __syncthreads();
    int cur = 0;
#pragma unroll
    for (int s = 0; s < NS; ++s) {
        if (s + 1 < NS) GLOADP((s + 1) * BK);
        bf16x8 a0 = *reinterpret_cast<bf16x8*>(&As[cur][m * SA + quad * 8]);
        bf16x8 a1 = *reinterpret_cast<bf16x8*>(&As[cur][(16 + m) * SA + quad * 8]);
#pragma unroll
        for (int t = 0; t < NTW; ++t) {
            const ushort_t* wp =
                Wpk + (((size_t)(wv * NTW + t) * NS + s) * 64 + lane) * 8;
            bf16x8 b = *reinterpret_cast<const bf16x8*>(wp);
            acc[0][t] = __builtin_amdgcn_mfma_f32_16x16x32_bf16(a0, b, acc[0][t], 0, 0, 0);
            acc[1][t] = __builtin_amdgcn_mfma_f32_16x16x32_bf16(a1, b, acc[1][t], 0, 0, 0);
        }
        if (s + 1 < NS) {
            LSTOREP(cur ^ 1);
            __syncthreads();
            cur ^= 1;
        }
    }
#undef GLOADP
#undef LSTOREP

#pragma unroll
    for (int f = 0; f < 2; ++f) {
#pragma unroll
        for (int t = 0; t < NTW; ++t) {
#pragma unroll
            for (int i = 0; i < 4; ++i) {
                int r = row0 + f * 16 + quad * 4 + i;
                int c = cbase + t * 16 + m;
                if (r < n) {
                    if constexpr (OUT_FP8)
                        ((unsigned char*)Cv)[(size_t)r * DC + c] = f2fp8(acc[f][t][i]);
                    else
                        ((ushort_t*)Cv)[(size_t)r * DC + c] = f2bf(acc[f][t][i]);
                }
            }
        }
    }
}

// ---------------------------------------------------------------------------
// CSR SpMM, one wave per row, 4-way group edge parallelism; 16-edge main
// loop with 4 gathers in flight (R9-proven).  Segments padded to 8 records.
// ---------------------------------------------------------------------------

// Layer 1: sup = fp8 e4m3 [n x 128], out h = bf16 [n x 128], bias + relu.
__global__ __launch_bounds__(256) void k_spmm1(const int2* __restrict__ rseg,
                                               const unsigned* __restrict__ ep4,
                                               const unsigned char* __restrict__ sup,
                                               const float* __restrict__ bias,
                                               ushort_t* __restrict__ h, int n) {
    const int w    = (blockIdx.x * 256 + threadIdx.x) >> 6;
    const int lane = threadIdx.x & 63;
    const int g    = lane >> 4;
    const int gl   = lane & 15;
    if (w >= n) return;
    const int2 seg = rseg[w];

    float a0 = 0.f, a1 = 0.f, a2 = 0.f, a3 = 0.f;
    float a4 = 0.f, a5 = 0.f, a6 = 0.f, a7 = 0.f;
    const int hoff = gl << 3;   // 8 fp8 dims per lane
    auto sel = [&](uint4 q) -> unsigned {
        unsigned r  = (g & 1) ? q.y : q.x;
        unsigned rr = (g & 1) ? q.w : q.z;
        return (g & 2) ? rr : r;
    };
    auto gld = [&](unsigned r) -> uint2 {
        return *reinterpret_cast<const uint2*>(
            sup + (((size_t)(r & 0xFFFFu)) << 7) + hoff);
    };
    auto acc8 = [&](unsigned r, uint2 v) {
        float ww = __half2float(__ushort_as_half((ushort_t)(r >> 16)));
        a0 = fmaf(ww, FP8CVT(v.x, 0), a0);
        a1 = fmaf(ww, FP8CVT(v.x, 1), a1);
        a2 = fmaf(ww, FP8CVT(v.x, 2), a2);
        a3 = fmaf(ww, FP8CVT(v.x, 3), a3);
        a4 = fmaf(ww, FP8CVT(v.y, 0), a4);
        a5 = fmaf(ww, FP8CVT(v.y, 1), a5);
        a6 = fmaf(ww, FP8CVT(v.y, 2), a6);
        a7 = fmaf(ww, FP8CVT(v.y, 3), a7);
    };
    int i = seg.x;
    for (; i + 16 <= seg.y; i += 16) {
        uint4 qa = *reinterpret_cast<const uint4*>(ep4 + i);
        uint4 qb = *reinterpret_cast<const uint4*>(ep4 + i + 4);
        uint4 qc = *reinterpret_cast<const uint4*>(ep4 + i + 8);
        uint4 qd = *reinterpret_cast<const uint4*>(ep4 + i + 12);
        unsigned r0 = sel(qa), r1 = sel(qb), r2 = sel(qc), r3 = sel(qd);
        uint2 v0 = gld(r0), v1 = gld(r1), v2 = gld(r2), v3 = gld(r3);
        acc8(r0, v0); acc8(r1, v1); acc8(r2, v2); acc8(r3, v3);
    }
    for (; i < seg.y; i += 8) {
        uint4 qa = *reinterpret_cast<const uint4*>(ep4 + i);
        uint4 qb = *reinterpret_cast<const uint4*>(ep4 + i + 4);
        unsigned r0 = sel(qa), r1 = sel(qb);
        uint2 v0 = gld(r0), v1 = gld(r1);
        acc8(r0, v0); acc8(r1, v1);
    }
    a0 += __shfl_xor(a0, 16); a0 += __shfl_xor(a0, 32);
    a1 += __shfl_xor(a1, 16); a1 += __shfl_xor(a1, 32);
    a2 += __shfl_xor(a2, 16); a2 += __shfl_xor(a2, 32);
    a3 += __shfl_xor(a3, 16); a3 += __shfl_xor(a3, 32);
    a4 += __shfl_xor(a4, 16); a4 += __shfl_xor(a4, 32);
    a5 += __shfl_xor(a5, 16); a5 += __shfl_xor(a5, 32);
    a6 += __shfl_xor(a6, 16); a6 += __shfl_xor(a6, 32);
    a7 += __shfl_xor(a7, 16); a7 += __shfl_xor(a7, 32);
    if (g == 0) {
        const int d = gl << 3;
        float4 bs0 = *reinterpret_cast<const float4*>(bias + d);
        float4 bs1 = *reinterpret_cast<const float4*>(bias + d + 4);
        a0 = fmaxf(a0 + bs0.x, 0.f); a1 = fmaxf(a1 + bs0.y, 0.f);
        a2 = fmaxf(a2 + bs0.z, 0.f); a3 = fmaxf(a3 + bs0.w, 0.f);
        a4 = fmaxf(a4 + bs1.x, 0.f); a5 = fmaxf(a5 + bs1.y, 0.f);
        a6 = fmaxf(a6 + bs1.z, 0.f); a7 = fmaxf(a7 + bs1.w, 0.f);
        uint4 pk;
        pk.x = (unsigned)f2bf(a0) | ((unsigned)f2bf(a1) << 16);
        pk.y = (unsigned)f2bf(a2) | ((unsigned)f2bf(a3) << 16);
        pk.z = (unsigned)f2bf(a4) | ((unsigned)f2bf(a5) << 16);
        pk.w = (unsigned)f2bf(a6) | ((unsigned)f2bf(a7) << 16);
        *reinterpret_cast<uint4*>(h + (size_t)w * HID_DIM + d) = pk;
    }
}

// Layer 2: sup = bf16 [n x 64], out = fp32 [n x 64], bias, no relu.
__global__ __launch_bounds__(256) void k_spmm2(const int2* __restrict__ rseg,
                                               const unsigned* __restrict__ ep4,
                                               const ushort_t* __restrict__ sup,
                                               const float* __restrict__ bias,
                                               float* __restrict__ out, int n) {
    const int w    = (blockIdx.x * 256 + threadIdx.x) >> 6;
    const int lane = threadIdx.x & 63;
    const int g    = lane >> 4;
    const int gl   = lane & 15;
    if (w >= n) return;
    const int2 seg = rseg[w];

    float a0 = 0.f, a1 = 0.f, a2 = 0.f, a3 = 0.f;
    const unsigned char* supb = (const unsigned char*)sup;
    const int hoff = gl << 3;   // 4 bf16 dims per lane
    auto sel = [&](uint4 q) -> unsigned {
        unsigned r  = (g & 1) ? q.y : q.x;
        unsigned rr = (g & 1) ? q.w : q.z;
        return (g & 2) ? rr : r;
    };
    auto gld = [&](unsigned r) -> uint2 {
        return *reinterpret_cast<const uint2*>(
            supb + (((size_t)(r & 0xFFFFu)) << 7) + hoff);
    };
    auto acc4 = [&](unsigned r, uint2 v) {
        float ww = __half2float(__ushort_as_half((ushort_t)(r >> 16)));
        a0 = fmaf(ww, __uint_as_float(v.x << 16), a0);
        a1 = fmaf(ww, __uint_as_float(v.x & 0xFFFF0000u), a1);
        a2 = fmaf(ww, __uint_as_float(v.y << 16), a2);
        a3 = fmaf(ww, __uint_as_float(v.y & 0xFFFF0000u), a3);
    };
    int i = seg.x;
    for (; i + 16 <= seg.y; i += 16) {
        uint4 qa = *reinterpret_cast<const uint4*>(ep4 + i);
        uint4 qb = *reinterpret_cast<const uint4*>(ep4 + i + 4);
        uint4 qc = *reinterpret_cast<const uint4*>(ep4 + i + 8);
        uint4 qd = *reinterpret_cast<const uint4*>(ep4 + i + 12);
        unsigned r0 = sel(qa), r1 = sel(qb), r2 = sel(qc), r3 = sel(qd);
        uint2 v0 = gld(r0), v1 = gld(r1), v2 = gld(r2), v3 = gld(r3);
        acc4(r0, v0); acc4(r1, v1); acc4(r2, v2); acc4(r3, v3);
    }
    for (; i < seg.y; i += 8) {
        uint4 qa = *reinterpret_cast<const uint4*>(ep4 + i);
        uint4 qb = *reinterpret_cast<const uint4*>(ep4 + i + 4);
        unsigned r0 = sel(qa), r1 = sel(qb);
        uint2 v0 = gld(r0), v1 = gld(r1);
        acc4(r0, v0); acc4(r1, v1);
    }
    a0 += __shfl_xor(a0, 16); a0 += __shfl_xor(a0, 32);
    a1 += __shfl_xor(a1, 16); a1 += __shfl_xor(a1, 32);
    a2 += __shfl_xor(a2, 16); a2 += __shfl_xor(a2, 32);
    a3 += __shfl_xor(a3, 16); a3 += __shfl_xor(a3, 32);
    if (g == 0) {
        const int d = gl << 2;
        float4 bs = *reinterpret_cast<const float4*>(bias + d);
        *reinterpret_cast<float4*>(out + (size_t)w * OUT_DIM + d) =
            make_float4(a0 + bs.x, a1 + bs.y, a2 + bs.z, a3 + bs.w);
    }
}

// Legacy SpMM (8-byte int2 records, fp32 weights) — fallback path only.
template <int D, bool RELU, bool OUT_BF16, bool SUP_FP8>
__global__ __launch_bounds__(256) void k_spmm_legacy(const int* __restrict__ rp,
                                                     const int2* __restrict__ ep,
                                                     const void* __restrict__ supv,
                                                     const float* __restrict__ bias,
                                                     void* __restrict__ outv, int n) {
    const int w    = (blockIdx.x * 256 + threadIdx.x) >> 6;
    const int lane = threadIdx.x & 63;
    if (w >= n) return;
    const int s = rp[w], e = rp[w + 1];

    if constexpr (D == 128) {
        const int d = lane * 2;
        float accx = 0.f, accy = 0.f;
        for (int i = s; i < e; ++i) {
            int2 r = ep[i];
            float ww = __int_as_float(r.y);
            if constexpr (SUP_FP8) {
                const unsigned char* sup = (const unsigned char*)supv;
                unsigned short u = *reinterpret_cast<const unsigned short*>(&sup[(size_t)r.x * D + d]);
                accx = fmaf(ww, fp82f((unsigned char)(u & 255)), accx);
                accy = fmaf(ww, fp82f((unsigned char)(u >> 8)), accy);
            } else {
                const ushort_t* sup = (const ushort_t*)supv;
                unsigned u = *reinterpret_cast<const unsigned*>(&sup[(size_t)r.x * D + d]);
                accx = fmaf(ww, __uint_as_float(u << 16), accx);
                accy = fmaf(ww, __uint_as_float(u & 0xFFFF0000u), accy);
            }
        }
        accx += bias[d]; accy += bias[d + 1];
        if (RELU) { accx = fmaxf(accx, 0.f); accy = fmaxf(accy, 0.f); }
        if constexpr (OUT_BF16) {
            unsigned pk = (unsigned)f2bf(accx) | ((unsigned)f2bf(accy) << 16);
            *reinterpret_cast<unsigned*>((ushort_t*)outv + (size_t)w * D + d) = pk;
        } else {
            *reinterpret_cast<float2*>((float*)outv + (size_t)w * D + d) =
                make_float2(accx, accy);
        }
    } else {
        const int d = lane;
        const ushort_t* sup = (const ushort_t*)supv;
        float acc = 0.f;
        for (int i = s; i < e; ++i) {
            int2 r = ep[i];
            acc = fmaf(__int_as_float(r.y), bf2f(sup[(size_t)r.x * D + d]), acc);
        }
        acc += bias[d];
        if (RELU) acc = fmaxf(acc, 0.f);
        if constexpr (OUT_BF16)
            ((ushort_t*)outv)[(size_t)w * D + d] = f2bf(acc);
        else
            ((float*)outv)[(size_t)w * D + d] = acc;
    }
}

// ---------------------------------------------------------------------------

extern "C" void kernel_launch(void* const* d_in, const int* in_sizes, int n_in,
                              void* d_out, int out_size, void* d_ws, size_t ws_size,
                              hipStream_t stream) {
    const float* x  = (const float*)d_in[0];
    const int*   ei = (const int*)d_in[1];
    const float* ew = (const float*)d_in[2];
    const float* W1 = (const float*)d_in[3];
    const float* b1 = (const float*)d_in[4];
    const float* W2 = (const float*)d_in[5];
    const float* b2 = (const float*)d_in[6];
    float* out = (float*)d_out;

    const int n = in_sizes[0] / IN_DIM;  // 50000
    const int E = in_sizes[2];           // 1600000
    const int* rows = ei;
    const int* cols = ei + E;

    char* ws = (char*)d_ws;
    size_t off = 0;
    auto alloc = [&](size_t bytes) -> void* {
        off = (off + 255) & ~(size_t)255;
        void* p = ws + off;
        off += bytes;
        return p;
    };
    // padded edge capacity: E + per-bucket slack
    const size_t epad = (size_t)E + (size_t)NBMAX * BSLACK;
    unsigned* ep4     = (unsigned*)alloc(epad * sizeof(unsigned));
    int2*     rseg    = (int2*)alloc((size_t)n * sizeof(int2));
    int*      bcnt    = (int*)alloc(NBMAX * sizeof(int));
    int*      bbase   = (int*)alloc((NBMAX + 1) * sizeof(int));
    int*      bfill   = (int*)alloc(NBMAX * sizeof(int));
    int*      done    = (int*)alloc(256);
    ushort_t* Wt1     = (ushort_t*)alloc((size_t)IN_DIM * HID_DIM * sizeof(ushort_t));
    ushort_t* Wpk2    = (ushort_t*)alloc((size_t)NE2 * 8 * sizeof(ushort_t));
    // shared region: ept (bin temp, epad*8B) | sup1 (n*128 fp8) | sup2 (n*64 bf16)
    size_t sup1_bytes = (size_t)n * HID_DIM;
    size_t sup2_bytes = (size_t)n * OUT_DIM * sizeof(ushort_t);
    size_t ept_bytes  = epad * sizeof(int2);
    size_t reg = sup1_bytes > ept_bytes ? sup1_bytes : ept_bytes;
    if (sup2_bytes > reg) reg = sup2_bytes;
    unsigned char* sup1 = (unsigned char*)alloc(reg);
    ushort_t* h    = (ushort_t*)alloc((size_t)n * HID_DIM * sizeof(ushort_t));
    ushort_t* sup2 = (ushort_t*)sup1;  // sup1 dead after spmm1
    int2*     ept  = (int2*)sup1;      // bin temp aliases sup1 (dead until gemm1)

    const int nbk  = (n + 127) / 128;
    const int nbh  = (E + BH_TILE - 1) / BH_TILE;
    const int binb = (E + BIN_TILE - 1) / BIN_TILE;
    const int gemb = (n + 127) / 128;
    const int pkb  = (n + 31) / 32;
    const int wb   = (IN_DIM * HID_DIM + NE2 + 255) / 256;

    // 1. weight prep (W1 transpose + W2 frag-pack) + zero bcnt/done
    k_wcvt2<<<wb, 256, 0, stream>>>(W1, Wt1, W2, Wpk2, bcnt, done);

    if (n <= 65536) {
        // 2. bucket hist + in-kernel scan (last-block pattern)
        k_bhist2<<<nbh, 256, 0, stream>>>(rows, bcnt, bbase, bfill, done, E, nbk, nbh);
        // 3-4. bin -> unbin
        k_bin<<<binb, 256, 0, stream>>>(rows, cols, ew, bfill, ept, E, nbk);
        k_unbin<<<nbk, 256, 0, stream>>>(bbase, bcnt, ept, ep4, rseg, n);
        // 5. gemm1 (BR=128): x @ W1 -> fp8 sup1
        k_gemm_mfma<IN_DIM, HID_DIM, false, true><<<gemb, 256, 0, stream>>>(x, Wt1, sup1, n);
        // 6. spmm1 (4-gather MLP) -> h bf16
        k_spmm1<<<(n + 3) / 4, 256, 0, stream>>>(rseg, ep4, sup1, b1, h, n);
        // 7. gemm2 (packed-W): h @ W2 -> bf16 sup2
        k_gemm_pk<HID_DIM, OUT_DIM, true, false><<<pkb, 256, 0, stream>>>(h, Wpk2, sup2, n);
        // 8. spmm2 (4-gather MLP) -> out
        k_spmm2<<<(n + 3) / 4, 256, 0, stream>>>(rseg, ep4, sup2, b2, out, n);
    } else {
        // --- fallback: row-level hist -> scan -> direct scatter (8B recs) ---
        int*  row_ptr  = (int*)alloc((size_t)(n + 1) * sizeof(int));
        int*  deg      = (int*)alloc((size_t)n * sizeof(int));
        int*  row_fill = (int*)alloc((size_t)n * sizeof(int));
        int*  bsum     = (int*)alloc(256 * sizeof(int));
        int*  bscn     = (int*)alloc(256 * sizeof(int));
        int2* ep8      = (int2*)alloc((size_t)E * sizeof(int2));
        const int nb = (n + SCAN_TILE - 1) / SCAN_TILE;
        k_zero<<<(n + 255) / 256, 256, 0, stream>>>(deg, n);
        k_hist<<<(E + 255) / 256, 256, 0, stream>>>(rows, deg, E);
        k_scan1<<<nb, 256, 0, stream>>>(deg, bsum, n);
        k_scan2<<<1, 256, 0, stream>>>(bsum, bscn, nb);
        k_scan3<<<nb, 256, 0, stream>>>(deg, bscn, row_ptr, row_fill, n, E);
        k_scatter<<<(E + 255) / 256, 256, 0, stream>>>(rows, cols, ew, row_fill, ep8, E);

        k_gemm_mfma<IN_DIM, HID_DIM, false, true><<<gemb, 256, 0, stream>>>(x, Wt1, sup1, n);
        k_spmm_legacy<HID_DIM, true, true, true><<<(n + 3) / 4, 256, 0, stream>>>(row_ptr, ep8, sup1, b1, h, n);
        k_gemm_pk<HID_DIM, OUT_DIM, true, false><<<pkb, 256, 0, stream>>>(h, Wpk2, (void*)sup2, n);
        k_spmm_legacy<OUT_DIM, false, false, false><<<(n + 3) / 4, 256, 0, stream>>>(row_ptr, ep8, sup2, b2, out, n);
    }
}